// Round 9
// baseline (90.314 us; speedup 1.0000x reference)
//
#include <hip/hip_runtime.h>
#include <hip/hip_bf16.h>

#define B_ 16
#define C_ 64
#define HW_ 4096              // H*W
#define K_ 1024
#define NELEM 4194304         // B*C*H*W
#define NBLK 1024             // 64 pixels per block

typedef __attribute__((ext_vector_type(8))) short bf16x8;
typedef __attribute__((ext_vector_type(4))) float f32x4;

static __device__ __forceinline__ short f2bf(float f) {
    __hip_bfloat16 h = __float2bfloat16(f);           // RNE, native cvt
    return (short)__builtin_bit_cast(unsigned short, h);
}

// ---- kernel 1: emb -> fragment-contiguous bf16(-2*emb) + e2' + cnt=0 -----
// Fragment layout (shorts): q*16384 + ch*2048 + (ct*2+half)*512 + lane*8,
// lane = kgrp*16 + prow; code = q*256+ch*32+ct*16+prow; dims = half*32+kgrp*8.
// A wave's 4 chunk-fragments are then coalesced dwordx4 at stride 512 shorts.
__global__ __launch_bounds__(256) void vq_prep(const float* __restrict__ emb,
                                               float* __restrict__ e2,
                                               short* __restrict__ emb_q,
                                               int* __restrict__ cnt) {
    const int id = blockIdx.x * 256 + threadIdx.x;    // 0..8191
    if (id == 0) *cnt = 0;
    {   // -2x scale is exact in bf16 (sign + exponent shift)
        const int code = id >> 3;
        const int c16  = id & 7;                      // 16B group in row
        const float4* src = (const float4*)(emb + (size_t)id * 8);
        float4 a = src[0], b = src[1];
        bf16x8 v;
        v[0]=f2bf(-2.f*a.x); v[1]=f2bf(-2.f*a.y); v[2]=f2bf(-2.f*a.z); v[3]=f2bf(-2.f*a.w);
        v[4]=f2bf(-2.f*b.x); v[5]=f2bf(-2.f*b.y); v[6]=f2bf(-2.f*b.z); v[7]=f2bf(-2.f*b.w);
        const int q    = code >> 8;
        const int ch   = (code >> 5) & 7;
        const int ct   = (code >> 4) & 1;
        const int prow = code & 15;
        const int half = c16 >> 2;
        const int kgrp = c16 & 3;
        const int dst = q * 16384 + ch * 2048 + (ct * 2 + half) * 512
                      + (kgrp * 16 + prow) * 8;
        *(bf16x8*)(emb_q + dst) = v;
    }
    if (id < K_) {
        const float4* row = (const float4*)(emb + (size_t)id * C_);
        float s0 = 0.f, s1 = 0.f, s2 = 0.f, s3 = 0.f;
        #pragma unroll
        for (int i = 0; i < C_ / 4; ++i) {
            float4 v = row[i];
            s0 = fmaf(v.x, v.x, s0);
            s1 = fmaf(v.y, v.y, s1);
            s2 = fmaf(v.z, v.z, s2);
            s3 = fmaf(v.w, v.w, s3);
        }
        e2[id] = 1.0f + ((s0 + s1) + (s2 + s3));   // keeps dist' > 0
    }
}

// ---- kernel 2: fused MFMA argmin + gather + q_st + loss (+last-block) ----
// Block = 256 thr = 4 waves, owns 64 consecutive pixels (same b).
// Wave qd scans K-quadrant [qd*256, qd*256+256) with A-fragments loaded
// GLOBAL->REG (fragment-contiguous emb_q, depth-2 register double-buffer,
// fully unrolled so all buffer indices are static). A-reuse = 4 (zf[4][2]).
// No emb LDS, no per-chunk barriers.
//   D[row=code][col=pixel] = 1 + |e|^2 - 2 z.e  (positive)
// Select: sortable int = (bits(dist) & ~1023) | k ; argmin = v_min_i32.
__global__ __launch_bounds__(256, 4) void vq_main(const float* __restrict__ z,
                                                  const float* __restrict__ emb,
                                                  const short* __restrict__ emb_q,
                                                  const float* __restrict__ e2,
                                                  float* __restrict__ out,
                                                  float* __restrict__ psum,
                                                  int* __restrict__ cnt) {
    __shared__ short zlds[64 * 64];    // 8 KB, [px][ch], col ^= (px&7)<<4
    __shared__ int   smin[4][64];
    __shared__ int   cidx[64];
    __shared__ float red[4];
    __shared__ int   isLast;

    const int tid  = threadIdx.x;
    const int lane = tid & 63;
    const int qd   = __builtin_amdgcn_readfirstlane(tid >> 6);  // wave = quadrant
    const int prow = lane & 15;        // code-in-tile row
    const int kgrp = lane >> 4;        // k-group 0..3

    const int blk = blockIdx.x;        // 0..1023
    const int b   = blk >> 6;          // 64 blocks per image
    const int hw0 = (blk & 63) * 64;
    const float* zp = z + (size_t)b * C_ * HW_ + hw0;   // + c*HW_ + p

    // ---- stage z -> swizzled LDS bf16 (each thread: 16 ch of one pixel) --
    {
        const int p  = tid & 63;
        const int c0 = tid >> 6;               // 0..3
        #pragma unroll
        for (int h = 0; h < 2; ++h) {
            const int cb = c0 * 16 + h * 8;    // channel base
            bf16x8 pack;
            #pragma unroll
            for (int i = 0; i < 8; ++i) pack[i] = f2bf(zp[(size_t)(cb + i) * HW_ + p]);
            const int wb = (p * 128 + ((cb * 2) ^ ((p & 7) << 4))) >> 1;
            *(bf16x8*)(zlds + wb) = pack;
        }
    }
    __syncthreads();

    // ---- z fragments (B operand): 4 pixel tiles x 2 K-halves ----
    bf16x8 zf[4][2];
    #pragma unroll
    for (int pt = 0; pt < 4; ++pt) {
        const int pp = pt * 16 + prow;
        #pragma unroll
        for (int ks = 0; ks < 2; ++ks) {
            const int rb = (pp * 128 + ((ks * 64 + kgrp * 16) ^ ((pp & 7) << 4))) >> 1;
            zf[pt][ks] = *(const bf16x8*)(zlds + rb);
        }
    }

    // ---- per-wave argmin over its 256-code quadrant, global->reg A ----
    const short* eq  = emb_q + qd * 16384 + lane * 8;   // + ch*2048 + f*512
    const float* e2q = e2 + qd * 256 + kgrp * 4;        // + ch*32 + ct*16

    bf16x8 A[2][4];
    f32x4  E[2][2];
    int best[4] = {0x7FFFFFFF, 0x7FFFFFFF, 0x7FFFFFFF, 0x7FFFFFFF};

    #pragma unroll
    for (int f = 0; f < 4; ++f) A[0][f] = *(const bf16x8*)(eq + f * 512);
    #pragma unroll
    for (int ct = 0; ct < 2; ++ct) E[0][ct] = *(const f32x4*)(e2q + ct * 16);

    #pragma unroll
    for (int ch = 0; ch < 8; ++ch) {            // FULL unroll: static indices
        const int cur = ch & 1;
        if (ch < 7) {                           // depth-2 prefetch
            const int nxt = cur ^ 1;
            #pragma unroll
            for (int f = 0; f < 4; ++f)
                A[nxt][f] = *(const bf16x8*)(eq + (ch + 1) * 2048 + f * 512);
            #pragma unroll
            for (int ct = 0; ct < 2; ++ct)
                E[nxt][ct] = *(const f32x4*)(e2q + (ch + 1) * 32 + ct * 16);
        }
        #pragma unroll
        for (int ct = 0; ct < 2; ++ct) {
            const bf16x8 a0 = A[cur][ct * 2 + 0];
            const bf16x8 a1 = A[cur][ct * 2 + 1];
            const f32x4  ev = E[cur][ct];
            const int korg = qd * 256 + ch * 32 + ct * 16 + kgrp * 4;
            #pragma unroll
            for (int pt = 0; pt < 4; ++pt) {
                f32x4 acc = ev;
                acc = __builtin_amdgcn_mfma_f32_16x16x32_bf16(a0, zf[pt][0], acc, 0, 0, 0);
                acc = __builtin_amdgcn_mfma_f32_16x16x32_bf16(a1, zf[pt][1], acc, 0, 0, 0);
                #pragma unroll
                for (int r = 0; r < 4; ++r) {
                    const int s = (__builtin_bit_cast(int, acc[r]) & ~1023) | (korg + r);
                    best[pt] = min(best[pt], s);
                }
            }
        }
    }

    // cross-lane combine over k-groups (bits 4,5 of lane)
    #pragma unroll
    for (int pt = 0; pt < 4; ++pt) {
        #pragma unroll
        for (int m = 16; m <= 32; m <<= 1)
            best[pt] = min(best[pt], __shfl_xor(best[pt], m));
        if (kgrp == 0) smin[qd][pt * 16 + prow] = best[pt];
    }
    __syncthreads();

    // cross-wave combine (4 quadrant-waves)
    if (tid < 64) {
        int bb = min(min(smin[0][tid], smin[1][tid]),
                     min(smin[2][tid], smin[3][tid]));
        cidx[tid] = bb & 1023;
    }
    __syncthreads();

    // ---- output phase: q_st = z + (q - z), partial loss ----
    float* op = out + (size_t)b * C_ * HW_ + hw0;
    const int p  = tid & 63;
    const int c0 = tid >> 6;                  // 0..3
    const float* qrow = emb + (size_t)cidx[p] * C_;
    float sq = 0.f;
    #pragma unroll
    for (int i = 0; i < 16; ++i) {
        const int c = c0 * 16 + i;
        const float zv   = zp[(size_t)c * HW_ + p];
        const float q    = qrow[c];
        const float diff = q - zv;            // matches reference op order
        op[(size_t)c * HW_ + p] = zv + diff;  // q_st = z + (q - z)
        sq = fmaf(diff, diff, sq);
    }
    #pragma unroll
    for (int off = 32; off; off >>= 1) sq += __shfl_xor(sq, off);
    if (lane == 0) red[tid >> 6] = sq;
    __syncthreads();
    if (tid == 0) {
        psum[blk] = (red[0] + red[1]) + (red[2] + red[3]);
        __threadfence();                      // psum visible device-wide
        isLast = (atomicAdd(cnt, 1) == NBLK - 1);
    }
    __syncthreads();

    // ---- last block reduces psum -> loss (fixed order => deterministic) --
    if (isLast) {
        __threadfence();
        float s = (psum[tid] + psum[tid + 256]) + (psum[tid + 512] + psum[tid + 768]);
        #pragma unroll
        for (int off = 32; off; off >>= 1) s += __shfl_xor(s, off);
        if (lane == 0) red[tid >> 6] = s;
        __syncthreads();
        if (tid == 0)
            out[NELEM] = 1.25f * ((red[0] + red[1]) + (red[2] + red[3])) / (float)NELEM;
    }
}

extern "C" void kernel_launch(void* const* d_in, const int* in_sizes, int n_in,
                              void* d_out, int out_size, void* d_ws, size_t ws_size,
                              hipStream_t stream) {
    const float* z   = (const float*)d_in[0];   // [16,64,64,64]
    const float* emb = (const float*)d_in[1];   // [1024,64]
    float* out = (float*)d_out;                 // [4194304 q_st] ++ [1 loss]

    float* psum  = (float*)d_ws;                // 1024 floats
    float* e2    = psum + NBLK;                 // 1024 floats (e2' = 1+|e|^2)
    int*   cnt   = (int*)(e2 + K_);             // 1 int (+pad to 16B)
    short* emb_q = (short*)(cnt + 4);           // 65536 bf16, fragment layout

    vq_prep<<<(K_ * C_) / (256 * 8), 256, 0, stream>>>(emb, e2, emb_q, cnt);
    vq_main<<<NBLK, 256, 0, stream>>>(z, emb, emb_q, e2, out, psum, cnt);
}

// Round 10
// 62.719 us; speedup vs baseline: 1.4400x; 1.4400x over previous
//
#include <hip/hip_runtime.h>
#include <hip/hip_bf16.h>

#define B_ 16
#define C_ 64
#define HW_ 4096              // H*W
#define K_ 1024
#define NELEM 4194304         // B*C*H*W
#define NBLK 1024             // 64 pixels per block

typedef __attribute__((ext_vector_type(8))) short bf16x8;
typedef __attribute__((ext_vector_type(4))) float f32x4;

static __device__ __forceinline__ short f2bf(float f) {
    __hip_bfloat16 h = __float2bfloat16(f);           // RNE, native cvt
    return (short)__builtin_bit_cast(unsigned short, h);
}

// ---- kernel 1: emb -> fragment-contiguous bf16(-2*emb) + e2' + cnt=0 -----
// Fragment layout (shorts): q*16384 + ch*2048 + (ct*2+half)*512 + lane*8,
// lane = kgrp*16 + prow; code = q*256+ch*32+ct*16+prow; dims = half*32+kgrp*8.
// A wave's fragments are coalesced 16B/lane loads at stride 512 shorts.
__global__ __launch_bounds__(256) void vq_prep(const float* __restrict__ emb,
                                               float* __restrict__ e2,
                                               short* __restrict__ emb_q,
                                               int* __restrict__ cnt) {
    const int id = blockIdx.x * 256 + threadIdx.x;    // 0..8191
    if (id == 0) *cnt = 0;
    {   // -2x scale is exact in bf16 (sign + exponent shift)
        const int code = id >> 3;
        const int c16  = id & 7;                      // 16B group in row
        const float4* src = (const float4*)(emb + (size_t)id * 8);
        float4 a = src[0], b = src[1];
        bf16x8 v;
        v[0]=f2bf(-2.f*a.x); v[1]=f2bf(-2.f*a.y); v[2]=f2bf(-2.f*a.z); v[3]=f2bf(-2.f*a.w);
        v[4]=f2bf(-2.f*b.x); v[5]=f2bf(-2.f*b.y); v[6]=f2bf(-2.f*b.z); v[7]=f2bf(-2.f*b.w);
        const int q    = code >> 8;
        const int ch   = (code >> 5) & 7;
        const int ct   = (code >> 4) & 1;
        const int prow = code & 15;
        const int half = c16 >> 2;
        const int kgrp = c16 & 3;
        const int dst = q * 16384 + ch * 2048 + (ct * 2 + half) * 512
                      + (kgrp * 16 + prow) * 8;
        *(bf16x8*)(emb_q + dst) = v;
    }
    if (id < K_) {
        const float4* row = (const float4*)(emb + (size_t)id * C_);
        float s0 = 0.f, s1 = 0.f, s2 = 0.f, s3 = 0.f;
        #pragma unroll
        for (int i = 0; i < C_ / 4; ++i) {
            float4 v = row[i];
            s0 = fmaf(v.x, v.x, s0);
            s1 = fmaf(v.y, v.y, s1);
            s2 = fmaf(v.z, v.z, s2);
            s3 = fmaf(v.w, v.w, s3);
        }
        e2[id] = 1.0f + ((s0 + s1) + (s2 + s3));   // keeps dist' > 0
    }
}

// ---- kernel 2: fused MFMA argmin + gather + q_st + loss (+last-block) ----
// Block = 256 thr = 4 waves, owns 64 consecutive pixels (same b).
// Wave qd scans K-quadrant [qd*256,...+256); A-fragments GLOBAL->REG from
// fragment-contiguous emb_q. NO explicit register double-buffer (R9's spill
// cause) — fully-unrolled loop with direct loads; compiler pipelines within
// the 256-reg cap of launch_bounds(256,2). A-reuse = 4 (zf[4][2]).
//   D[row=code][col=pixel] = 1 + |e|^2 - 2 z.e  (positive)
// Select: sortable int = (bits(dist) & ~1023) | k ; argmin = v_min_i32.
__global__ __launch_bounds__(256, 2) void vq_main(const float* __restrict__ z,
                                                  const float* __restrict__ emb,
                                                  const short* __restrict__ emb_q,
                                                  const float* __restrict__ e2,
                                                  float* __restrict__ out,
                                                  float* __restrict__ psum,
                                                  int* __restrict__ cnt) {
    __shared__ short zlds[64 * 64];    // 8 KB, [px][ch], col ^= (px&7)<<4
    __shared__ int   smin[4][64];
    __shared__ int   cidx[64];
    __shared__ float red[4];
    __shared__ int   isLast;

    const int tid  = threadIdx.x;
    const int lane = tid & 63;
    const int qd   = __builtin_amdgcn_readfirstlane(tid >> 6);  // wave = quadrant
    const int prow = lane & 15;        // code-in-tile row
    const int kgrp = lane >> 4;        // k-group 0..3

    const int blk = blockIdx.x;        // 0..1023
    const int b   = blk >> 6;          // 64 blocks per image
    const int hw0 = (blk & 63) * 64;
    const float* zp = z + (size_t)b * C_ * HW_ + hw0;   // + c*HW_ + p

    // ---- stage z -> swizzled LDS bf16 (each thread: 16 ch of one pixel) --
    {
        const int p  = tid & 63;
        const int c0 = tid >> 6;               // 0..3
        #pragma unroll
        for (int h = 0; h < 2; ++h) {
            const int cb = c0 * 16 + h * 8;    // channel base
            bf16x8 pack;
            #pragma unroll
            for (int i = 0; i < 8; ++i) pack[i] = f2bf(zp[(size_t)(cb + i) * HW_ + p]);
            const int wb = (p * 128 + ((cb * 2) ^ ((p & 7) << 4))) >> 1;
            *(bf16x8*)(zlds + wb) = pack;
        }
    }
    __syncthreads();

    // ---- z fragments (B operand): 4 pixel tiles x 2 K-halves ----
    bf16x8 zf[4][2];
    #pragma unroll
    for (int pt = 0; pt < 4; ++pt) {
        const int pp = pt * 16 + prow;
        #pragma unroll
        for (int ks = 0; ks < 2; ++ks) {
            const int rb = (pp * 128 + ((ks * 64 + kgrp * 16) ^ ((pp & 7) << 4))) >> 1;
            zf[pt][ks] = *(const bf16x8*)(zlds + rb);
        }
    }

    // ---- per-wave argmin over its 256-code quadrant, global->reg A ----
    const short* eq  = emb_q + qd * 16384 + lane * 8;   // + ch*2048 + f*512
    const float* e2q = e2 + qd * 256 + kgrp * 4;        // + ch*32 + ct*16
    int best[4] = {0x7FFFFFFF, 0x7FFFFFFF, 0x7FFFFFFF, 0x7FFFFFFF};

    #pragma unroll
    for (int ch = 0; ch < 8; ++ch) {
        #pragma unroll
        for (int ct = 0; ct < 2; ++ct) {
            const bf16x8 a0 = *(const bf16x8*)(eq + ch * 2048 + (ct * 2 + 0) * 512);
            const bf16x8 a1 = *(const bf16x8*)(eq + ch * 2048 + (ct * 2 + 1) * 512);
            const f32x4  ev = *(const f32x4*)(e2q + ch * 32 + ct * 16);
            const int korg = qd * 256 + ch * 32 + ct * 16 + kgrp * 4;
            #pragma unroll
            for (int pt = 0; pt < 4; ++pt) {
                f32x4 acc = ev;
                acc = __builtin_amdgcn_mfma_f32_16x16x32_bf16(a0, zf[pt][0], acc, 0, 0, 0);
                acc = __builtin_amdgcn_mfma_f32_16x16x32_bf16(a1, zf[pt][1], acc, 0, 0, 0);
                #pragma unroll
                for (int r = 0; r < 4; ++r) {
                    const int s = (__builtin_bit_cast(int, acc[r]) & ~1023) | (korg + r);
                    best[pt] = min(best[pt], s);
                }
            }
        }
    }

    // cross-lane combine over k-groups (bits 4,5 of lane)
    #pragma unroll
    for (int pt = 0; pt < 4; ++pt) {
        #pragma unroll
        for (int m = 16; m <= 32; m <<= 1)
            best[pt] = min(best[pt], __shfl_xor(best[pt], m));
        if (kgrp == 0) smin[qd][pt * 16 + prow] = best[pt];
    }
    __syncthreads();

    // cross-wave combine (4 quadrant-waves)
    if (tid < 64) {
        int bb = min(min(smin[0][tid], smin[1][tid]),
                     min(smin[2][tid], smin[3][tid]));
        cidx[tid] = bb & 1023;
    }
    __syncthreads();

    // ---- output phase: q_st = z + (q - z), partial loss ----
    float* op = out + (size_t)b * C_ * HW_ + hw0;
    const int p  = tid & 63;
    const int c0 = tid >> 6;                  // 0..3
    const float* qrow = emb + (size_t)cidx[p] * C_;
    float sq = 0.f;
    #pragma unroll
    for (int i = 0; i < 16; ++i) {
        const int c = c0 * 16 + i;
        const float zv   = zp[(size_t)c * HW_ + p];
        const float q    = qrow[c];
        const float diff = q - zv;            // matches reference op order
        op[(size_t)c * HW_ + p] = zv + diff;  // q_st = z + (q - z)
        sq = fmaf(diff, diff, sq);
    }
    #pragma unroll
    for (int off = 32; off; off >>= 1) sq += __shfl_xor(sq, off);
    if (lane == 0) red[tid >> 6] = sq;
    __syncthreads();
    if (tid == 0) {
        psum[blk] = (red[0] + red[1]) + (red[2] + red[3]);
        __threadfence();                      // psum visible device-wide
        isLast = (atomicAdd(cnt, 1) == NBLK - 1);
    }
    __syncthreads();

    // ---- last block reduces psum -> loss (fixed order => deterministic) --
    if (isLast) {
        __threadfence();
        float s = (psum[tid] + psum[tid + 256]) + (psum[tid + 512] + psum[tid + 768]);
        #pragma unroll
        for (int off = 32; off; off >>= 1) s += __shfl_xor(s, off);
        if (lane == 0) red[tid >> 6] = s;
        __syncthreads();
        if (tid == 0)
            out[NELEM] = 1.25f * ((red[0] + red[1]) + (red[2] + red[3])) / (float)NELEM;
    }
}

extern "C" void kernel_launch(void* const* d_in, const int* in_sizes, int n_in,
                              void* d_out, int out_size, void* d_ws, size_t ws_size,
                              hipStream_t stream) {
    const float* z   = (const float*)d_in[0];   // [16,64,64,64]
    const float* emb = (const float*)d_in[1];   // [1024,64]
    float* out = (float*)d_out;                 // [4194304 q_st] ++ [1 loss]

    float* psum  = (float*)d_ws;                // 1024 floats
    float* e2    = psum + NBLK;                 // 1024 floats (e2' = 1+|e|^2)
    int*   cnt   = (int*)(e2 + K_);             // 1 int (+pad to 16B)
    short* emb_q = (short*)(cnt + 4);           // 65536 bf16, fragment layout

    vq_prep<<<(K_ * C_) / (256 * 8), 256, 0, stream>>>(emb, e2, emb_q, cnt);
    vq_main<<<NBLK, 256, 0, stream>>>(z, emb, emb_q, e2, out, psum, cnt);
}